// Round 9
// baseline (244.686 us; speedup 1.0000x reference)
//
#include <hip/hip_runtime.h>
#include <hip/hip_fp16.h>

#define N_NODES 100000
#define N_EDGES 1600000
#define BN_EPS 1e-5f

#define NBUCK 256          // dst buckets
#define NPB   391          // nodes per bucket (ceil(100000/256)); last has 295
#define BCAP  8192         // edge capacity per bucket (mean 6250, ~24 sigma margin)
#define EPB_BIN 4096       // edges per k_bin block
#define NBLK_BIN ((N_EDGES + EPB_BIN - 1) / EPB_BIN)   // 391

#define P1_NBLK 512        // k_pull1 grid (grid-stride)
#define K7_NBLK 512        // k7_xw2 grid (grid-stride over 6250 groups)

// ---- workspace layout (32-bit units) ----
#define OFF_GCUR   0            // 256 ints: bucket fill cursors (into binned)
#define OFF_CNT    256          // N ints
#define OFF_DINV   100352       // N floats
#define OFF_OFFS   200448       // N ints (gapped CSR offsets into ebuf)
#define OFF_EBUF   300544       // NBUCK*BCAP = 2,097,152 ints (gapped)
#define OFF_STATS1 2397696      // 128 floats: sum[64], sumsq[64]
#define OFF_STATS2 2397824      // 4 floats: s0,s1,q0,q1
#define OFF_HS1    2398016      // half[N*64] = 3.2M units (head aliases binned pre-k3)
#define OFF_BINNED OFF_HS1      // int[NBUCK*BCAP] = 2,097,152 < 3,200,000
#define OFF_OUT1   5598016      // half[N*64] = 3.2M units
#define OFF_HS2    8798016      // N*2 floats
#define OFF_OUT2   8998016      // N*2 floats
// total 9,198,016 * 4B = 36.8 MB

typedef _Float16 f16x8 __attribute__((ext_vector_type(8)));
typedef float    f32x4 __attribute__((ext_vector_type(4)));

__device__ inline float4 cvt4(uint2 v) {
    __half2 a = *(__half2*)&v.x, b = *(__half2*)&v.y;
    float2 fa = __half22float2(a), fb = __half22float2(b);
    return make_float4(fa.x, fa.y, fb.x, fb.y);
}

// K0: init bucket cursors to slice bases; zero stat accumulators
__global__ __launch_bounds__(256) void k0_init(int* __restrict__ gcur,
                                               float* __restrict__ stats) {
    int t = threadIdx.x;
    gcur[t] = t * BCAP;
    if (t < 132) stats[t] = 0.f;   // stats1(128)+stats2(4) contiguous
}

// K1: radix partition edges into 256 dst-buckets; store packed (src | ldst<<17)
__global__ __launch_bounds__(256) void k_bin(
        const int* __restrict__ src, const int* __restrict__ dst,
        int* __restrict__ gcur, int* __restrict__ binned) {
    __shared__ int hist[NBUCK];
    __shared__ int lcur[NBUCK];
    int t = threadIdx.x, b = blockIdx.x;
    hist[t] = 0;
    __syncthreads();
    int e0 = b * EPB_BIN;
    int pkreg[16], bkreg[16];
#pragma unroll
    for (int i = 0; i < 16; ++i) {
        int e = e0 + t + i * 256;              // coalesced
        if (e < N_EDGES) {
            int s = src[e], d = dst[e];
            int bk = d / NPB;
            bkreg[i] = bk;
            pkreg[i] = s | ((d - bk * NPB) << 17);
            atomicAdd(&hist[bk], 1);
        } else bkreg[i] = -1;
    }
    __syncthreads();
    int h = hist[t];
    lcur[t] = (h > 0) ? atomicAdd(&gcur[t], h) : 0;   // reserve contiguous run
    __syncthreads();
#pragma unroll
    for (int i = 0; i < 16; ++i) {
        if (bkreg[i] >= 0) {
            int bk = bkreg[i];
            int pos = atomicAdd(&lcur[bk], 1);
            if (pos < (bk + 1) * BCAP)          // overflow guard (never taken)
                binned[pos] = pkreg[i];
        }
    }
}

// K2: per-bucket CSR build (LDS-only histogram/scan/cursors) + cnt/offs/dinv
__global__ __launch_bounds__(256) void k_csr(
        const int* __restrict__ gcur, const int* __restrict__ binned,
        int* __restrict__ cnt, float* __restrict__ dinv,
        int* __restrict__ offs, int* __restrict__ ebuf) {
    int b = blockIdx.x, t = threadIdx.x;
    int nb0 = b * NPB;
    int nn = min(NPB, N_NODES - nb0);          // 391 (or 295 for last)
    __shared__ int lcnt[NPB];
    __shared__ int lcur[NPB];
    __shared__ int sc[512];
    for (int i = t; i < NPB; i += 256) lcnt[i] = 0;
    __syncthreads();
    int base = b * BCAP;
    int m = min(gcur[b] - base, BCAP);
    for (int j = t; j < m; j += 256)
        atomicAdd(&lcnt[((unsigned)binned[base + j]) >> 17], 1);
    __syncthreads();
    // exclusive scan of lcnt[0..NPB) via Hillis-Steele over 512 slots
    sc[t] = (t < NPB) ? lcnt[t] : 0;
    sc[256 + t] = (256 + t < NPB) ? lcnt[256 + t] : 0;
    __syncthreads();
    for (int off = 1; off < 512; off <<= 1) {
        int v0 = (t >= off) ? sc[t - off] : 0;
        int i1 = t + 256;
        int v1 = (i1 >= off) ? sc[i1 - off] : 0;
        __syncthreads();
        sc[t] += v0; sc[i1] += v1;
        __syncthreads();
    }
    for (int i = t; i < nn; i += 256) {
        int c = lcnt[i];
        int excl = sc[i] - c;
        lcur[i] = excl;
        offs[nb0 + i] = base + excl;           // gapped global CSR offset
        cnt[nb0 + i] = c;
        dinv[nb0 + i] = rsqrtf((float)(1 + c));
    }
    __syncthreads();
    for (int j = t; j < m; j += 256) {
        unsigned v = (unsigned)binned[base + j];
        int pos = atomicAdd(&lcur[v >> 17], 1);
        ebuf[base + pos] = (int)(v & 0x1FFFFu); // confined to 32KB slice
    }
}

// K3: hs1 = fp16( (u_S @ w1) * dinv[row] ) via MFMA.
// One wave per 16-row group: 8 loop-invariant B frags (w1 in VGPRs),
// 2 A frags from u (fp32->fp16), 8 x mfma_f32_16x16x32_f16, no LDS/barriers.
__global__ __launch_bounds__(256) void k3_xw1(
        const float* __restrict__ u, const float* __restrict__ w1g,
        const float* __restrict__ dinv, __half* __restrict__ hs1) {
    int t = threadIdx.x;
    int lane = t & 63, wid = t >> 6;
    int g = blockIdx.x * 4 + wid;              // 16-row group id
    if (g >= N_NODES / 16) return;             // wave-uniform exit
    int r = lane & 15, kb = lane >> 4;

    f16x8 bf[4][2];                            // [col-tile][k-half]
#pragma unroll
    for (int ct = 0; ct < 4; ++ct) {
#pragma unroll
        for (int kh = 0; kh < 2; ++kh) {
            int c = ct * 16 + r;
            int k0 = kh * 32 + kb * 8;
            f16x8 b;
#pragma unroll
            for (int i = 0; i < 8; ++i) b[i] = (_Float16)w1g[(k0 + i) * 64 + c];
            bf[ct][kh] = b;
        }
    }

    const float* up = u + (size_t)g * 16 * 64;
    f16x8 af[2];
#pragma unroll
    for (int kh = 0; kh < 2; ++kh) {
        const float* p = up + r * 64 + kh * 32 + kb * 8;
        float4 v0 = *(const float4*)p;
        float4 v1 = *(const float4*)(p + 4);
        f16x8 a;
        a[0] = (_Float16)v0.x; a[1] = (_Float16)v0.y;
        a[2] = (_Float16)v0.z; a[3] = (_Float16)v0.w;
        a[4] = (_Float16)v1.x; a[5] = (_Float16)v1.y;
        a[6] = (_Float16)v1.z; a[7] = (_Float16)v1.w;
        af[kh] = a;
    }

    f32x4 acc[4];
#pragma unroll
    for (int ct = 0; ct < 4; ++ct) { acc[ct][0]=0.f; acc[ct][1]=0.f; acc[ct][2]=0.f; acc[ct][3]=0.f; }
#pragma unroll
    for (int ct = 0; ct < 4; ++ct) {
        acc[ct] = __builtin_amdgcn_mfma_f32_16x16x32_f16(af[0], bf[ct][0], acc[ct], 0, 0, 0);
        acc[ct] = __builtin_amdgcn_mfma_f32_16x16x32_f16(af[1], bf[ct][1], acc[ct], 0, 0, 0);
    }

    int r0 = g * 16;
    float4 dv = *(const float4*)&dinv[r0 + kb * 4];
    float dvv[4] = {dv.x, dv.y, dv.z, dv.w};
#pragma unroll
    for (int ct = 0; ct < 4; ++ct) {
#pragma unroll
        for (int reg = 0; reg < 4; ++reg) {
            int row = r0 + kb * 4 + reg;
            int col = ct * 16 + r;
            hs1[(size_t)row * 64 + col] = __float2half(acc[ct][reg] * dvv[reg]);
        }
    }
}

// K4: pull aggregation layer 1 + fused BN1 stats.
// Grid-stride, 16 threads/node, 4 halves each; 4x-unrolled gather for MLP.
__global__ __launch_bounds__(256) void k_pull1(
        const int* __restrict__ offs, const int* __restrict__ cnt,
        const int* __restrict__ ebuf, const float* __restrict__ dinv,
        const __half* __restrict__ hs1, __half* __restrict__ out1,
        float* __restrict__ stats) {
    const uint2* h4 = (const uint2*)hs1;      // 4 halves per uint2, 16 per row
    int sub = threadIdx.x & 15;
    int stride = gridDim.x * blockDim.x;
    float ps[4] = {0.f, 0.f, 0.f, 0.f};
    float pq[4] = {0.f, 0.f, 0.f, 0.f};
    for (int idx = blockIdx.x * blockDim.x + threadIdx.x; idx < N_NODES * 16;
         idx += stride) {
        int d = idx >> 4;
        float4 acc = cvt4(h4[d * 16 + sub]);  // self-loop term
        int base = offs[d], c = cnt[d];
        int j = 0;
        for (; j + 4 <= c; j += 4) {          // 4 gathers in flight
            int s0 = ebuf[base + j],     s1 = ebuf[base + j + 1];
            int s2 = ebuf[base + j + 2], s3 = ebuf[base + j + 3];
            float4 v0 = cvt4(h4[s0 * 16 + sub]);
            float4 v1 = cvt4(h4[s1 * 16 + sub]);
            float4 v2 = cvt4(h4[s2 * 16 + sub]);
            float4 v3 = cvt4(h4[s3 * 16 + sub]);
            acc.x += (v0.x + v1.x) + (v2.x + v3.x);
            acc.y += (v0.y + v1.y) + (v2.y + v3.y);
            acc.z += (v0.z + v1.z) + (v2.z + v3.z);
            acc.w += (v0.w + v1.w) + (v2.w + v3.w);
        }
        for (; j < c; ++j) {
            float4 v = cvt4(h4[ebuf[base + j] * 16 + sub]);
            acc.x += v.x; acc.y += v.y; acc.z += v.z; acc.w += v.w;
        }
        float di = dinv[d];
        acc.x *= di; acc.y *= di; acc.z *= di; acc.w *= di;
        __half2 lo = __floats2half2_rn(acc.x, acc.y);
        __half2 hi = __floats2half2_rn(acc.z, acc.w);
        uint2 o; o.x = *(unsigned*)&lo; o.y = *(unsigned*)&hi;
        ((uint2*)out1)[d * 16 + sub] = o;
        ps[0] += acc.x; pq[0] = fmaf(acc.x, acc.x, pq[0]);
        ps[1] += acc.y; pq[1] = fmaf(acc.y, acc.y, pq[1]);
        ps[2] += acc.z; pq[2] = fmaf(acc.z, acc.z, pq[2]);
        ps[3] += acc.w; pq[3] = fmaf(acc.w, acc.w, pq[3]);
    }
    // reduce over the 4 node-slots per wave (lane bits 4,5); sub preserved
#pragma unroll
    for (int m = 16; m < 64; m <<= 1) {
#pragma unroll
        for (int jj = 0; jj < 4; ++jj) {
            ps[jj] += __shfl_xor(ps[jj], m);
            pq[jj] += __shfl_xor(pq[jj], m);
        }
    }
    __shared__ float red[4][128];
    int lane = threadIdx.x & 63, wv = threadIdx.x >> 6;
    if (lane < 16) {
#pragma unroll
        for (int jj = 0; jj < 4; ++jj) {
            red[wv][lane * 4 + jj] = ps[jj];
            red[wv][64 + lane * 4 + jj] = pq[jj];
        }
    }
    __syncthreads();
    if (threadIdx.x < 128) {
        int tt = threadIdx.x;
        float v = red[0][tt] + red[1][tt] + red[2][tt] + red[3][tt];
        unsafeAtomicAdd(&stats[tt], v);       // stats[c]=sum, stats[64+c]=sumsq
    }
}

// K6: s1 = relu(bn1(out1)); hs2 = (s1 @ w2) * dinv[row], via MFMA.
// 16 rows/group/wave, grid-strided; B = w2 zero-padded to 16 cols.
__global__ __launch_bounds__(256) void k7_xw2(
        const __half* __restrict__ out1, const float* __restrict__ stats,
        const float* __restrict__ g1, const float* __restrict__ beta1,
        const float* __restrict__ w2, const float* __restrict__ dinv,
        float* __restrict__ hs2) {
    __shared__ float lsc[64], lsh[64];
    int t = threadIdx.x;
    if (t < 64) {
        float invn = 1.f / (float)N_NODES;
        float m = stats[t] * invn;
        float v = stats[64 + t] * invn - m * m;
        float inv = rsqrtf(v + BN_EPS);
        float sc = g1[t] * inv;
        lsc[t] = sc;
        lsh[t] = beta1[t] - m * sc;
    }
    __syncthreads();
    int lane = t & 63, wv = t >> 6;
    int r = lane & 15, kb = lane >> 4;
    // loop-invariant B frags and BN coefficients for this lane's k-slices
    f16x8 bf[2];
    float scr[2][8], shr[2][8];
#pragma unroll
    for (int kh = 0; kh < 2; ++kh) {
        int k0 = kh * 32 + kb * 8;
        f16x8 b;
#pragma unroll
        for (int i = 0; i < 8; ++i) {
            b[i] = (r < 2) ? (_Float16)w2[(k0 + i) * 2 + r] : (_Float16)0.f;
            scr[kh][i] = lsc[k0 + i];
            shr[kh][i] = lsh[k0 + i];
        }
        bf[kh] = b;
    }
    const int NGRP = N_NODES / 16;             // 6250
    int wid = blockIdx.x * 4 + wv;
    for (int g = wid; g < NGRP; g += K7_NBLK * 4) {
        f32x4 acc; acc[0]=0.f; acc[1]=0.f; acc[2]=0.f; acc[3]=0.f;
#pragma unroll
        for (int kh = 0; kh < 2; ++kh) {
            uint4 av = *(const uint4*)(out1 + (size_t)(g * 16 + r) * 64 + kh * 32 + kb * 8);
            unsigned w[4] = {av.x, av.y, av.z, av.w};
            f16x8 a;
#pragma unroll
            for (int h = 0; h < 4; ++h) {
                float2 f = __half22float2(*(__half2*)&w[h]);
                float y0 = fmaxf(fmaf(f.x, scr[kh][2*h],   shr[kh][2*h]),   0.f);
                float y1 = fmaxf(fmaf(f.y, scr[kh][2*h+1], shr[kh][2*h+1]), 0.f);
                a[2*h]   = (_Float16)y0;
                a[2*h+1] = (_Float16)y1;
            }
            acc = __builtin_amdgcn_mfma_f32_16x16x32_f16(a, bf[kh], acc, 0, 0, 0);
        }
        if (r < 2) {
            float4 dv = *(const float4*)&dinv[g * 16 + kb * 4];
            float dvv[4] = {dv.x, dv.y, dv.z, dv.w};
#pragma unroll
            for (int reg = 0; reg < 4; ++reg) {
                int row = g * 16 + kb * 4 + reg;
                hs2[row * 2 + r] = acc[reg] * dvv[reg];
            }
        }
    }
}

// K7: pull aggregation layer 2 + fused BN2 stats
__global__ __launch_bounds__(256) void k_pull2(
        const int* __restrict__ offs, const int* __restrict__ cnt,
        const int* __restrict__ ebuf, const float* __restrict__ dinv,
        const float* __restrict__ hs2, float* __restrict__ out2,
        float* __restrict__ stats2) {
    int d = blockIdx.x * blockDim.x + threadIdx.x;
    float o0 = 0.f, o1 = 0.f;
    if (d < N_NODES) {
        const float2* h2 = (const float2*)hs2;
        float2 self = h2[d];
        o0 = self.x; o1 = self.y;
        int base = offs[d], c = cnt[d];
        for (int j = 0; j < c; ++j) {
            int s = ebuf[base + j];
            float2 v = h2[s];
            o0 += v.x; o1 += v.y;
        }
        float di = dinv[d];
        o0 *= di; o1 *= di;
        ((float2*)out2)[d] = make_float2(o0, o1);
    }
    // block-reduce sums & sumsq (threads past N contribute 0)
    float s0 = o0, s1 = o1, q0 = o0 * o0, q1 = o1 * o1;
#pragma unroll
    for (int m = 32; m; m >>= 1) {
        s0 += __shfl_down(s0, m); s1 += __shfl_down(s1, m);
        q0 += __shfl_down(q0, m); q1 += __shfl_down(q1, m);
    }
    __shared__ float red[4][4];
    int wv = threadIdx.x >> 6;
    if ((threadIdx.x & 63) == 0) {
        red[0][wv] = s0; red[1][wv] = s1; red[2][wv] = q0; red[3][wv] = q1;
    }
    __syncthreads();
    if (threadIdx.x < 4) {
        int i = threadIdx.x;
        float v = red[i][0] + red[i][1] + red[i][2] + red[i][3];
        unsafeAtomicAdd(&stats2[i], v);
    }
}

// K8: BN2 + sigmoid + softmax epilogue
__global__ __launch_bounds__(256) void k10_head(
        const float* __restrict__ out2, const float* __restrict__ stats2,
        const float* __restrict__ g2, const float* __restrict__ beta2,
        float* __restrict__ out) {
    int r = blockIdx.x * blockDim.x + threadIdx.x;
    if (r >= N_NODES) return;
    float invn = 1.f / (float)N_NODES;
    float m0 = stats2[0] * invn, m1 = stats2[1] * invn;
    float v0 = stats2[2] * invn - m0 * m0;
    float v1 = stats2[3] * invn - m1 * m1;
    float i0 = rsqrtf(v0 + BN_EPS), i1 = rsqrtf(v1 + BN_EPS);
    float sc0 = g2[0] * i0, sc1 = g2[1] * i1;
    float sh0 = beta2[0] - m0 * sc0, sh1 = beta2[1] - m1 * sc1;
    float2 x = ((const float2*)out2)[r];
    float y0 = fmaf(x.x, sc0, sh0), y1 = fmaf(x.y, sc1, sh1);
    out[r * 2] = 1.f / (1.f + __expf(-y0));
    out[r * 2 + 1] = 1.f / (1.f + __expf(-y1));
    out[2 * N_NODES + r * 2] = 1.f / (1.f + __expf(y1 - y0));
    out[2 * N_NODES + r * 2 + 1] = 1.f / (1.f + __expf(y0 - y1));
}

extern "C" void kernel_launch(void* const* d_in, const int* in_sizes, int n_in,
                              void* d_out, int out_size, void* d_ws, size_t ws_size,
                              hipStream_t stream) {
    const int*   edge  = (const int*)d_in[0];          // (2,E): [0,E)=src, [E,2E)=dst
    const float* u_S   = (const float*)d_in[1];
    const float* w1    = (const float*)d_in[2];
    const float* g1    = (const float*)d_in[4];
    const float* beta1 = (const float*)d_in[5];
    const float* w2    = (const float*)d_in[6];
    const float* g2    = (const float*)d_in[8];
    const float* beta2 = (const float*)d_in[9];
    float* out = (float*)d_out;

    float*  ws     = (float*)d_ws;
    int*    gcur   = (int*)(ws + OFF_GCUR);
    int*    cnt    = (int*)(ws + OFF_CNT);
    float*  dinv   = ws + OFF_DINV;
    int*    offs   = (int*)(ws + OFF_OFFS);
    int*    ebuf   = (int*)(ws + OFF_EBUF);
    float*  stats1 = ws + OFF_STATS1;
    float*  stats2 = ws + OFF_STATS2;
    __half* hs1    = (__half*)(ws + OFF_HS1);
    int*    binned = (int*)(ws + OFF_BINNED);   // alias of hs1 head; dead before k3_xw1
    __half* out1   = (__half*)(ws + OFF_OUT1);
    float*  hs2    = ws + OFF_HS2;
    float*  out2   = ws + OFF_OUT2;

    const int* src = edge;
    const int* dst = edge + N_EDGES;

    k0_init<<<1, 256, 0, stream>>>(gcur, stats1);
    k_bin<<<NBLK_BIN, 256, 0, stream>>>(src, dst, gcur, binned);
    k_csr<<<NBUCK, 256, 0, stream>>>(gcur, binned, cnt, dinv, offs, ebuf);
    k3_xw1<<<(N_NODES / 16 + 3) / 4, 256, 0, stream>>>(u_S, w1, dinv, hs1);
    k_pull1<<<P1_NBLK, 256, 0, stream>>>(offs, cnt, ebuf, dinv, hs1, out1, stats1);
    k7_xw2<<<K7_NBLK, 256, 0, stream>>>(out1, stats1, g1, beta1, w2, dinv, hs2);
    k_pull2<<<(N_NODES + 255) / 256, 256, 0, stream>>>(offs, cnt, ebuf, dinv, hs2, out2, stats2);
    k10_head<<<(N_NODES + 255) / 256, 256, 0, stream>>>(out2, stats2, g2, beta2, out);
}

// Round 11
// 241.013 us; speedup vs baseline: 1.0152x; 1.0152x over previous
//
#include <hip/hip_runtime.h>
#include <hip/hip_fp16.h>

#define N_NODES 100000
#define N_EDGES 1600000
#define BN_EPS 1e-5f

#define NBUCK 256          // dst buckets
#define NPB   391          // nodes per bucket (ceil(100000/256)); last has 295
#define BCAP  8192         // edge capacity per bucket (mean 6250, ~24 sigma margin)
#define EPB_BIN 4096       // edges per k_bin block
#define NBLK_BIN ((N_EDGES + EPB_BIN - 1) / EPB_BIN)   // 391

#define P1_NBLK 2048       // k_pull1 grid: 8 blocks/CU -> full wave occupancy
#define K7_NBLK 1563       // k7_xw2 grid: 6250 groups / 4 waves per block

// ---- workspace layout (32-bit units) ----
#define OFF_GCUR   0            // 256 ints: bucket fill cursors (into binned)
#define OFF_CNT    256          // N ints
#define OFF_DINV   100352       // N floats
#define OFF_OFFS   200448       // N ints (gapped CSR offsets into ebuf)
#define OFF_EBUF   300544       // NBUCK*BCAP = 2,097,152 ints (gapped)
#define OFF_STATS1 2397696      // 128 floats: sum[64], sumsq[64]
#define OFF_STATS2 2397824      // 4 floats: s0,s1,q0,q1
#define OFF_HS1    2398016      // half[N*64] = 3.2M units (head aliases binned pre-k3)
#define OFF_BINNED OFF_HS1      // int[NBUCK*BCAP] = 2,097,152 < 3,200,000
#define OFF_OUT1   5598016      // half[N*64] = 3.2M units
#define OFF_HS2    8798016      // N*2 floats
#define OFF_OUT2   8998016      // N*2 floats
// total 9,198,016 * 4B = 36.8 MB

typedef _Float16 f16x8 __attribute__((ext_vector_type(8)));
typedef float    f32x4 __attribute__((ext_vector_type(4)));

__device__ inline float4 cvt4(uint2 v) {
    __half2 a = *(__half2*)&v.x, b = *(__half2*)&v.y;
    float2 fa = __half22float2(a), fb = __half22float2(b);
    return make_float4(fa.x, fa.y, fb.x, fb.y);
}

// K0: init bucket cursors to slice bases; zero stat accumulators
__global__ __launch_bounds__(256) void k0_init(int* __restrict__ gcur,
                                               float* __restrict__ stats) {
    int t = threadIdx.x;
    gcur[t] = t * BCAP;
    if (t < 132) stats[t] = 0.f;   // stats1(128)+stats2(4) contiguous
}

// K1: radix partition edges into 256 dst-buckets; store packed (src | ldst<<17)
__global__ __launch_bounds__(256) void k_bin(
        const int* __restrict__ src, const int* __restrict__ dst,
        int* __restrict__ gcur, int* __restrict__ binned) {
    __shared__ int hist[NBUCK];
    __shared__ int lcur[NBUCK];
    int t = threadIdx.x, b = blockIdx.x;
    hist[t] = 0;
    __syncthreads();
    int e0 = b * EPB_BIN;
    int pkreg[16], bkreg[16];
#pragma unroll
    for (int i = 0; i < 16; ++i) {
        int e = e0 + t + i * 256;              // coalesced
        if (e < N_EDGES) {
            int s = src[e], d = dst[e];
            int bk = d / NPB;
            bkreg[i] = bk;
            pkreg[i] = s | ((d - bk * NPB) << 17);
            atomicAdd(&hist[bk], 1);
        } else bkreg[i] = -1;
    }
    __syncthreads();
    int h = hist[t];
    lcur[t] = (h > 0) ? atomicAdd(&gcur[t], h) : 0;   // reserve contiguous run
    __syncthreads();
#pragma unroll
    for (int i = 0; i < 16; ++i) {
        if (bkreg[i] >= 0) {
            int bk = bkreg[i];
            int pos = atomicAdd(&lcur[bk], 1);
            if (pos < (bk + 1) * BCAP)          // overflow guard (never taken)
                binned[pos] = pkreg[i];
        }
    }
}

// K2: per-bucket CSR build (LDS-only histogram/scan/cursors) + cnt/offs/dinv
__global__ __launch_bounds__(256) void k_csr(
        const int* __restrict__ gcur, const int* __restrict__ binned,
        int* __restrict__ cnt, float* __restrict__ dinv,
        int* __restrict__ offs, int* __restrict__ ebuf) {
    int b = blockIdx.x, t = threadIdx.x;
    int nb0 = b * NPB;
    int nn = min(NPB, N_NODES - nb0);          // 391 (or 295 for last)
    __shared__ int lcnt[NPB];
    __shared__ int lcur[NPB];
    __shared__ int sc[512];
    for (int i = t; i < NPB; i += 256) lcnt[i] = 0;
    __syncthreads();
    int base = b * BCAP;
    int m = min(gcur[b] - base, BCAP);
    for (int j = t; j < m; j += 256)
        atomicAdd(&lcnt[((unsigned)binned[base + j]) >> 17], 1);
    __syncthreads();
    // exclusive scan of lcnt[0..NPB) via Hillis-Steele over 512 slots
    sc[t] = (t < NPB) ? lcnt[t] : 0;
    sc[256 + t] = (256 + t < NPB) ? lcnt[256 + t] : 0;
    __syncthreads();
    for (int off = 1; off < 512; off <<= 1) {
        int v0 = (t >= off) ? sc[t - off] : 0;
        int i1 = t + 256;
        int v1 = (i1 >= off) ? sc[i1 - off] : 0;
        __syncthreads();
        sc[t] += v0; sc[i1] += v1;
        __syncthreads();
    }
    for (int i = t; i < nn; i += 256) {
        int c = lcnt[i];
        int excl = sc[i] - c;
        lcur[i] = excl;
        offs[nb0 + i] = base + excl;           // gapped global CSR offset
        cnt[nb0 + i] = c;
        dinv[nb0 + i] = rsqrtf((float)(1 + c));
    }
    __syncthreads();
    for (int j = t; j < m; j += 256) {
        unsigned v = (unsigned)binned[base + j];
        int pos = atomicAdd(&lcur[v >> 17], 1);
        ebuf[base + pos] = (int)(v & 0x1FFFFu); // confined to 32KB slice
    }
}

// K3: hs1 = fp16( (u_S @ w1) * dinv[row] ) via MFMA.
__global__ __launch_bounds__(256) void k3_xw1(
        const float* __restrict__ u, const float* __restrict__ w1g,
        const float* __restrict__ dinv, __half* __restrict__ hs1) {
    int t = threadIdx.x;
    int lane = t & 63, wid = t >> 6;
    int g = blockIdx.x * 4 + wid;              // 16-row group id
    if (g >= N_NODES / 16) return;             // wave-uniform exit
    int r = lane & 15, kb = lane >> 4;

    f16x8 bf[4][2];                            // [col-tile][k-half]
#pragma unroll
    for (int ct = 0; ct < 4; ++ct) {
#pragma unroll
        for (int kh = 0; kh < 2; ++kh) {
            int c = ct * 16 + r;
            int k0 = kh * 32 + kb * 8;
            f16x8 b;
#pragma unroll
            for (int i = 0; i < 8; ++i) b[i] = (_Float16)w1g[(k0 + i) * 64 + c];
            bf[ct][kh] = b;
        }
    }

    const float* up = u + (size_t)g * 16 * 64;
    f16x8 af[2];
#pragma unroll
    for (int kh = 0; kh < 2; ++kh) {
        const float* p = up + r * 64 + kh * 32 + kb * 8;
        float4 v0 = *(const float4*)p;
        float4 v1 = *(const float4*)(p + 4);
        f16x8 a;
        a[0] = (_Float16)v0.x; a[1] = (_Float16)v0.y;
        a[2] = (_Float16)v0.z; a[3] = (_Float16)v0.w;
        a[4] = (_Float16)v1.x; a[5] = (_Float16)v1.y;
        a[6] = (_Float16)v1.z; a[7] = (_Float16)v1.w;
        af[kh] = a;
    }

    f32x4 acc[4];
#pragma unroll
    for (int ct = 0; ct < 4; ++ct) { acc[ct][0]=0.f; acc[ct][1]=0.f; acc[ct][2]=0.f; acc[ct][3]=0.f; }
#pragma unroll
    for (int ct = 0; ct < 4; ++ct) {
        acc[ct] = __builtin_amdgcn_mfma_f32_16x16x32_f16(af[0], bf[ct][0], acc[ct], 0, 0, 0);
        acc[ct] = __builtin_amdgcn_mfma_f32_16x16x32_f16(af[1], bf[ct][1], acc[ct], 0, 0, 0);
    }

    int r0 = g * 16;
    float4 dv = *(const float4*)&dinv[r0 + kb * 4];
    float dvv[4] = {dv.x, dv.y, dv.z, dv.w};
#pragma unroll
    for (int ct = 0; ct < 4; ++ct) {
#pragma unroll
        for (int reg = 0; reg < 4; ++reg) {
            int row = r0 + kb * 4 + reg;
            int col = ct * 16 + r;
            hs1[(size_t)row * 64 + col] = __float2half(acc[ct][reg] * dvv[reg]);
        }
    }
}

// K4: pull aggregation layer 1 + fused BN1 stats.
// Grid-stride, 16 threads/node, 4 halves each; 4x-unrolled gather for MLP.
__global__ __launch_bounds__(256) void k_pull1(
        const int* __restrict__ offs, const int* __restrict__ cnt,
        const int* __restrict__ ebuf, const float* __restrict__ dinv,
        const __half* __restrict__ hs1, __half* __restrict__ out1,
        float* __restrict__ stats) {
    const uint2* h4 = (const uint2*)hs1;      // 4 halves per uint2, 16 per row
    int sub = threadIdx.x & 15;
    int stride = gridDim.x * blockDim.x;
    float ps[4] = {0.f, 0.f, 0.f, 0.f};
    float pq[4] = {0.f, 0.f, 0.f, 0.f};
    for (int idx = blockIdx.x * blockDim.x + threadIdx.x; idx < N_NODES * 16;
         idx += stride) {
        int d = idx >> 4;
        float4 acc = cvt4(h4[d * 16 + sub]);  // self-loop term
        int base = offs[d], c = cnt[d];
        int j = 0;
        for (; j + 4 <= c; j += 4) {          // 4 gathers in flight
            int s0 = ebuf[base + j],     s1 = ebuf[base + j + 1];
            int s2 = ebuf[base + j + 2], s3 = ebuf[base + j + 3];
            float4 v0 = cvt4(h4[s0 * 16 + sub]);
            float4 v1 = cvt4(h4[s1 * 16 + sub]);
            float4 v2 = cvt4(h4[s2 * 16 + sub]);
            float4 v3 = cvt4(h4[s3 * 16 + sub]);
            acc.x += (v0.x + v1.x) + (v2.x + v3.x);
            acc.y += (v0.y + v1.y) + (v2.y + v3.y);
            acc.z += (v0.z + v1.z) + (v2.z + v3.z);
            acc.w += (v0.w + v1.w) + (v2.w + v3.w);
        }
        for (; j < c; ++j) {
            float4 v = cvt4(h4[ebuf[base + j] * 16 + sub]);
            acc.x += v.x; acc.y += v.y; acc.z += v.z; acc.w += v.w;
        }
        float di = dinv[d];
        acc.x *= di; acc.y *= di; acc.z *= di; acc.w *= di;
        __half2 lo = __floats2half2_rn(acc.x, acc.y);
        __half2 hi = __floats2half2_rn(acc.z, acc.w);
        uint2 o; o.x = *(unsigned*)&lo; o.y = *(unsigned*)&hi;
        ((uint2*)out1)[d * 16 + sub] = o;
        ps[0] += acc.x; pq[0] = fmaf(acc.x, acc.x, pq[0]);
        ps[1] += acc.y; pq[1] = fmaf(acc.y, acc.y, pq[1]);
        ps[2] += acc.z; pq[2] = fmaf(acc.z, acc.z, pq[2]);
        ps[3] += acc.w; pq[3] = fmaf(acc.w, acc.w, pq[3]);
    }
    // reduce over the 4 node-slots per wave (lane bits 4,5); sub preserved
#pragma unroll
    for (int m = 16; m < 64; m <<= 1) {
#pragma unroll
        for (int jj = 0; jj < 4; ++jj) {
            ps[jj] += __shfl_xor(ps[jj], m);
            pq[jj] += __shfl_xor(pq[jj], m);
        }
    }
    __shared__ float red[4][128];
    int lane = threadIdx.x & 63, wv = threadIdx.x >> 6;
    if (lane < 16) {
#pragma unroll
        for (int jj = 0; jj < 4; ++jj) {
            red[wv][lane * 4 + jj] = ps[jj];
            red[wv][64 + lane * 4 + jj] = pq[jj];
        }
    }
    __syncthreads();
    if (threadIdx.x < 128) {
        int tt = threadIdx.x;
        float v = red[0][tt] + red[1][tt] + red[2][tt] + red[3][tt];
        unsafeAtomicAdd(&stats[tt], v);       // stats[c]=sum, stats[64+c]=sumsq
    }
}

// K6: s1 = relu(bn1(out1)); hs2 = (s1 @ w2) * dinv[row], via MFMA.
// 16 rows/group/wave, grid-strided; B = w2 zero-padded to 16 cols.
__global__ __launch_bounds__(256) void k7_xw2(
        const __half* __restrict__ out1, const float* __restrict__ stats,
        const float* __restrict__ g1, const float* __restrict__ beta1,
        const float* __restrict__ w2, const float* __restrict__ dinv,
        float* __restrict__ hs2) {
    __shared__ float lsc[64], lsh[64];
    int t = threadIdx.x;
    if (t < 64) {
        float invn = 1.f / (float)N_NODES;
        float m = stats[t] * invn;
        float v = stats[64 + t] * invn - m * m;
        float inv = rsqrtf(v + BN_EPS);
        float sc = g1[t] * inv;
        lsc[t] = sc;
        lsh[t] = beta1[t] - m * sc;
    }
    __syncthreads();
    int lane = t & 63, wv = t >> 6;
    int r = lane & 15, kb = lane >> 4;
    // loop-invariant B frags and BN coefficients for this lane's k-slices
    f16x8 bf[2];
    float scr[2][8], shr[2][8];
#pragma unroll
    for (int kh = 0; kh < 2; ++kh) {
        int k0 = kh * 32 + kb * 8;
        f16x8 b;
#pragma unroll
        for (int i = 0; i < 8; ++i) {
            b[i] = (r < 2) ? (_Float16)w2[(k0 + i) * 2 + r] : (_Float16)0.f;
            scr[kh][i] = lsc[k0 + i];
            shr[kh][i] = lsh[k0 + i];
        }
        bf[kh] = b;
    }
    const int NGRP = N_NODES / 16;             // 6250
    int wid = blockIdx.x * 4 + wv;
    for (int g = wid; g < NGRP; g += K7_NBLK * 4) {
        f32x4 acc; acc[0]=0.f; acc[1]=0.f; acc[2]=0.f; acc[3]=0.f;
#pragma unroll
        for (int kh = 0; kh < 2; ++kh) {
            uint4 av = *(const uint4*)(out1 + (size_t)(g * 16 + r) * 64 + kh * 32 + kb * 8);
            unsigned w[4] = {av.x, av.y, av.z, av.w};
            f16x8 a;
#pragma unroll
            for (int h = 0; h < 4; ++h) {
                float2 f = __half22float2(*(__half2*)&w[h]);
                float y0 = fmaxf(fmaf(f.x, scr[kh][2*h],   shr[kh][2*h]),   0.f);
                float y1 = fmaxf(fmaf(f.y, scr[kh][2*h+1], shr[kh][2*h+1]), 0.f);
                a[2*h]   = (_Float16)y0;
                a[2*h+1] = (_Float16)y1;
            }
            acc = __builtin_amdgcn_mfma_f32_16x16x32_f16(a, bf[kh], acc, 0, 0, 0);
        }
        if (r < 2) {
            float4 dv = *(const float4*)&dinv[g * 16 + kb * 4];
            float dvv[4] = {dv.x, dv.y, dv.z, dv.w};
#pragma unroll
            for (int reg = 0; reg < 4; ++reg) {
                int row = g * 16 + kb * 4 + reg;
                hs2[row * 2 + r] = acc[reg] * dvv[reg];
            }
        }
    }
}

// K7: pull aggregation layer 2 + fused BN2 stats
__global__ __launch_bounds__(256) void k_pull2(
        const int* __restrict__ offs, const int* __restrict__ cnt,
        const int* __restrict__ ebuf, const float* __restrict__ dinv,
        const float* __restrict__ hs2, float* __restrict__ out2,
        float* __restrict__ stats2) {
    int d = blockIdx.x * blockDim.x + threadIdx.x;
    float o0 = 0.f, o1 = 0.f;
    if (d < N_NODES) {
        const float2* h2 = (const float2*)hs2;
        float2 self = h2[d];
        o0 = self.x; o1 = self.y;
        int base = offs[d], c = cnt[d];
        for (int j = 0; j < c; ++j) {
            int s = ebuf[base + j];
            float2 v = h2[s];
            o0 += v.x; o1 += v.y;
        }
        float di = dinv[d];
        o0 *= di; o1 *= di;
        ((float2*)out2)[d] = make_float2(o0, o1);
    }
    // block-reduce sums & sumsq (threads past N contribute 0)
    float s0 = o0, s1 = o1, q0 = o0 * o0, q1 = o1 * o1;
#pragma unroll
    for (int m = 32; m; m >>= 1) {
        s0 += __shfl_down(s0, m); s1 += __shfl_down(s1, m);
        q0 += __shfl_down(q0, m); q1 += __shfl_down(q1, m);
    }
    __shared__ float red[4][4];
    int wv = threadIdx.x >> 6;
    if ((threadIdx.x & 63) == 0) {
        red[0][wv] = s0; red[1][wv] = s1; red[2][wv] = q0; red[3][wv] = q1;
    }
    __syncthreads();
    if (threadIdx.x < 4) {
        int i = threadIdx.x;
        float v = red[i][0] + red[i][1] + red[i][2] + red[i][3];
        unsafeAtomicAdd(&stats2[i], v);
    }
}

// K8: BN2 + sigmoid + softmax epilogue
__global__ __launch_bounds__(256) void k10_head(
        const float* __restrict__ out2, const float* __restrict__ stats2,
        const float* __restrict__ g2, const float* __restrict__ beta2,
        float* __restrict__ out) {
    int r = blockIdx.x * blockDim.x + threadIdx.x;
    if (r >= N_NODES) return;
    float invn = 1.f / (float)N_NODES;
    float m0 = stats2[0] * invn, m1 = stats2[1] * invn;
    float v0 = stats2[2] * invn - m0 * m0;
    float v1 = stats2[3] * invn - m1 * m1;
    float i0 = rsqrtf(v0 + BN_EPS), i1 = rsqrtf(v1 + BN_EPS);
    float sc0 = g2[0] * i0, sc1 = g2[1] * i1;
    float sh0 = beta2[0] - m0 * sc0, sh1 = beta2[1] - m1 * sc1;
    float2 x = ((const float2*)out2)[r];
    float y0 = fmaf(x.x, sc0, sh0), y1 = fmaf(x.y, sc1, sh1);
    out[r * 2] = 1.f / (1.f + __expf(-y0));
    out[r * 2 + 1] = 1.f / (1.f + __expf(-y1));
    out[2 * N_NODES + r * 2] = 1.f / (1.f + __expf(y1 - y0));
    out[2 * N_NODES + r * 2 + 1] = 1.f / (1.f + __expf(y0 - y1));
}

extern "C" void kernel_launch(void* const* d_in, const int* in_sizes, int n_in,
                              void* d_out, int out_size, void* d_ws, size_t ws_size,
                              hipStream_t stream) {
    const int*   edge  = (const int*)d_in[0];          // (2,E): [0,E)=src, [E,2E)=dst
    const float* u_S   = (const float*)d_in[1];
    const float* w1    = (const float*)d_in[2];
    const float* g1    = (const float*)d_in[4];
    const float* beta1 = (const float*)d_in[5];
    const float* w2    = (const float*)d_in[6];
    const float* g2    = (const float*)d_in[8];
    const float* beta2 = (const float*)d_in[9];
    float* out = (float*)d_out;

    float*  ws     = (float*)d_ws;
    int*    gcur   = (int*)(ws + OFF_GCUR);
    int*    cnt    = (int*)(ws + OFF_CNT);
    float*  dinv   = ws + OFF_DINV;
    int*    offs   = (int*)(ws + OFF_OFFS);
    int*    ebuf   = (int*)(ws + OFF_EBUF);
    float*  stats1 = ws + OFF_STATS1;
    float*  stats2 = ws + OFF_STATS2;
    __half* hs1    = (__half*)(ws + OFF_HS1);
    int*    binned = (int*)(ws + OFF_BINNED);   // alias of hs1 head; dead before k3_xw1
    __half* out1   = (__half*)(ws + OFF_OUT1);
    float*  hs2    = ws + OFF_HS2;
    float*  out2   = ws + OFF_OUT2;

    const int* src = edge;
    const int* dst = edge + N_EDGES;

    k0_init<<<1, 256, 0, stream>>>(gcur, stats1);
    k_bin<<<NBLK_BIN, 256, 0, stream>>>(src, dst, gcur, binned);
    k_csr<<<NBUCK, 256, 0, stream>>>(gcur, binned, cnt, dinv, offs, ebuf);
    k3_xw1<<<(N_NODES / 16 + 3) / 4, 256, 0, stream>>>(u_S, w1, dinv, hs1);
    k_pull1<<<P1_NBLK, 256, 0, stream>>>(offs, cnt, ebuf, dinv, hs1, out1, stats1);
    k7_xw2<<<K7_NBLK, 256, 0, stream>>>(out1, stats1, g1, beta1, w2, dinv, hs2);
    k_pull2<<<(N_NODES + 255) / 256, 256, 0, stream>>>(offs, cnt, ebuf, dinv, hs2, out2, stats2);
    k10_head<<<(N_NODES + 255) / 256, 256, 0, stream>>>(out2, stats2, g2, beta2, out);
}

// Round 12
// 211.067 us; speedup vs baseline: 1.1593x; 1.1419x over previous
//
#include <hip/hip_runtime.h>
#include <hip/hip_fp16.h>

#define N_NODES 100000
#define N_EDGES 1600000
#define BN_EPS 1e-5f

#define NBUCK 256          // dst buckets
#define NPB   391          // nodes per bucket (ceil(100000/256)); last has 295
#define BCAP  8192         // edge capacity per bucket (mean 6250, ~24 sigma margin)
#define EPB_BIN 4096       // edges per k_bin block
#define NBLK_BIN ((N_EDGES + EPB_BIN - 1) / EPB_BIN)   // 391

#define K7_NBLK 1563       // k7_xw2 grid: 6250 groups / 4 waves per block

// ---- workspace layout (32-bit units) ----
#define OFF_GCUR   0            // 256 ints: bucket fill cursors (into binned)
#define OFF_CNT    256          // N ints
#define OFF_DINV   100352       // N floats
#define OFF_OFFS   200448       // N ints (gapped CSR offsets into ebuf)
#define OFF_EBUF   300544       // NBUCK*BCAP = 2,097,152 ints (gapped)
#define OFF_STATS1 2397696      // 128 floats: sum[64], sumsq[64]
#define OFF_STATS2 2397824      // 4 floats: s0,s1,q0,q1
#define OFF_HS1    2398016      // half[N*64] = 3.2M units (head aliases binned pre-k3)
#define OFF_BINNED OFF_HS1      // int[NBUCK*BCAP] = 2,097,152 < 3,200,000
#define OFF_OUT1   5598016      // half[N*64] = 3.2M units
#define OFF_HS2    8798016      // N*2 floats
#define OFF_OUT2   8998016      // N*2 floats
// total 9,198,016 * 4B = 36.8 MB

typedef _Float16 f16x8 __attribute__((ext_vector_type(8)));
typedef float    f32x4 __attribute__((ext_vector_type(4)));

__device__ inline void cvt8(uint4 v, float* f) {
    float2 a = __half22float2(*(__half2*)&v.x);
    float2 b = __half22float2(*(__half2*)&v.y);
    float2 c = __half22float2(*(__half2*)&v.z);
    float2 d = __half22float2(*(__half2*)&v.w);
    f[0] = a.x; f[1] = a.y; f[2] = b.x; f[3] = b.y;
    f[4] = c.x; f[5] = c.y; f[6] = d.x; f[7] = d.y;
}

// K0: init bucket cursors to slice bases; zero stat accumulators
__global__ __launch_bounds__(256) void k0_init(int* __restrict__ gcur,
                                               float* __restrict__ stats) {
    int t = threadIdx.x;
    gcur[t] = t * BCAP;
    if (t < 132) stats[t] = 0.f;   // stats1(128)+stats2(4) contiguous
}

// K1: radix partition edges into 256 dst-buckets; store packed (src | ldst<<17)
__global__ __launch_bounds__(256) void k_bin(
        const int* __restrict__ src, const int* __restrict__ dst,
        int* __restrict__ gcur, int* __restrict__ binned) {
    __shared__ int hist[NBUCK];
    __shared__ int lcur[NBUCK];
    int t = threadIdx.x, b = blockIdx.x;
    hist[t] = 0;
    __syncthreads();
    int e0 = b * EPB_BIN;
    int pkreg[16], bkreg[16];
#pragma unroll
    for (int i = 0; i < 16; ++i) {
        int e = e0 + t + i * 256;              // coalesced
        if (e < N_EDGES) {
            int s = src[e], d = dst[e];
            int bk = d / NPB;
            bkreg[i] = bk;
            pkreg[i] = s | ((d - bk * NPB) << 17);
            atomicAdd(&hist[bk], 1);
        } else bkreg[i] = -1;
    }
    __syncthreads();
    int h = hist[t];
    lcur[t] = (h > 0) ? atomicAdd(&gcur[t], h) : 0;   // reserve contiguous run
    __syncthreads();
#pragma unroll
    for (int i = 0; i < 16; ++i) {
        if (bkreg[i] >= 0) {
            int bk = bkreg[i];
            int pos = atomicAdd(&lcur[bk], 1);
            if (pos < (bk + 1) * BCAP)          // overflow guard (never taken)
                binned[pos] = pkreg[i];
        }
    }
}

// K2: per-bucket CSR build (LDS-only histogram/scan/cursors) + cnt/offs/dinv
__global__ __launch_bounds__(256) void k_csr(
        const int* __restrict__ gcur, const int* __restrict__ binned,
        int* __restrict__ cnt, float* __restrict__ dinv,
        int* __restrict__ offs, int* __restrict__ ebuf) {
    int b = blockIdx.x, t = threadIdx.x;
    int nb0 = b * NPB;
    int nn = min(NPB, N_NODES - nb0);          // 391 (or 295 for last)
    __shared__ int lcnt[NPB];
    __shared__ int lcur[NPB];
    __shared__ int sc[512];
    for (int i = t; i < NPB; i += 256) lcnt[i] = 0;
    __syncthreads();
    int base = b * BCAP;
    int m = min(gcur[b] - base, BCAP);
    for (int j = t; j < m; j += 256)
        atomicAdd(&lcnt[((unsigned)binned[base + j]) >> 17], 1);
    __syncthreads();
    // exclusive scan of lcnt[0..NPB) via Hillis-Steele over 512 slots
    sc[t] = (t < NPB) ? lcnt[t] : 0;
    sc[256 + t] = (256 + t < NPB) ? lcnt[256 + t] : 0;
    __syncthreads();
    for (int off = 1; off < 512; off <<= 1) {
        int v0 = (t >= off) ? sc[t - off] : 0;
        int i1 = t + 256;
        int v1 = (i1 >= off) ? sc[i1 - off] : 0;
        __syncthreads();
        sc[t] += v0; sc[i1] += v1;
        __syncthreads();
    }
    for (int i = t; i < nn; i += 256) {
        int c = lcnt[i];
        int excl = sc[i] - c;
        lcur[i] = excl;
        offs[nb0 + i] = base + excl;           // gapped global CSR offset
        cnt[nb0 + i] = c;
        dinv[nb0 + i] = rsqrtf((float)(1 + c));
    }
    __syncthreads();
    for (int j = t; j < m; j += 256) {
        unsigned v = (unsigned)binned[base + j];
        int pos = atomicAdd(&lcur[v >> 17], 1);
        ebuf[base + pos] = (int)(v & 0x1FFFFu); // confined to 32KB slice
    }
}

// K3: hs1 = fp16( (u_S @ w1) * dinv[row] ) via MFMA.
__global__ __launch_bounds__(256) void k3_xw1(
        const float* __restrict__ u, const float* __restrict__ w1g,
        const float* __restrict__ dinv, __half* __restrict__ hs1) {
    int t = threadIdx.x;
    int lane = t & 63, wid = t >> 6;
    int g = blockIdx.x * 4 + wid;              // 16-row group id
    if (g >= N_NODES / 16) return;             // wave-uniform exit
    int r = lane & 15, kb = lane >> 4;

    f16x8 bf[4][2];                            // [col-tile][k-half]
#pragma unroll
    for (int ct = 0; ct < 4; ++ct) {
#pragma unroll
        for (int kh = 0; kh < 2; ++kh) {
            int c = ct * 16 + r;
            int k0 = kh * 32 + kb * 8;
            f16x8 b;
#pragma unroll
            for (int i = 0; i < 8; ++i) b[i] = (_Float16)w1g[(k0 + i) * 64 + c];
            bf[ct][kh] = b;
        }
    }

    const float* up = u + (size_t)g * 16 * 64;
    f16x8 af[2];
#pragma unroll
    for (int kh = 0; kh < 2; ++kh) {
        const float* p = up + r * 64 + kh * 32 + kb * 8;
        float4 v0 = *(const float4*)p;
        float4 v1 = *(const float4*)(p + 4);
        f16x8 a;
        a[0] = (_Float16)v0.x; a[1] = (_Float16)v0.y;
        a[2] = (_Float16)v0.z; a[3] = (_Float16)v0.w;
        a[4] = (_Float16)v1.x; a[5] = (_Float16)v1.y;
        a[6] = (_Float16)v1.z; a[7] = (_Float16)v1.w;
        af[kh] = a;
    }

    f32x4 acc[4];
#pragma unroll
    for (int ct = 0; ct < 4; ++ct) { acc[ct][0]=0.f; acc[ct][1]=0.f; acc[ct][2]=0.f; acc[ct][3]=0.f; }
#pragma unroll
    for (int ct = 0; ct < 4; ++ct) {
        acc[ct] = __builtin_amdgcn_mfma_f32_16x16x32_f16(af[0], bf[ct][0], acc[ct], 0, 0, 0);
        acc[ct] = __builtin_amdgcn_mfma_f32_16x16x32_f16(af[1], bf[ct][1], acc[ct], 0, 0, 0);
    }

    int r0 = g * 16;
    float4 dv = *(const float4*)&dinv[r0 + kb * 4];
    float dvv[4] = {dv.x, dv.y, dv.z, dv.w};
#pragma unroll
    for (int ct = 0; ct < 4; ++ct) {
#pragma unroll
        for (int reg = 0; reg < 4; ++reg) {
            int row = r0 + kb * 4 + reg;
            int col = ct * 16 + r;
            hs1[(size_t)row * 64 + col] = __float2half(acc[ct][reg] * dvv[reg]);
        }
    }
}

// K4: pull aggregation layer 1. 8 threads/node, uint4 (16B = 8 halves) each.
// Round-8 structure (one node per thread-group, 2-deep index prefetch).
__global__ __launch_bounds__(256) void k_pull1(
        const int* __restrict__ offs, const int* __restrict__ cnt,
        const int* __restrict__ ebuf, const float* __restrict__ dinv,
        const __half* __restrict__ hs1, __half* __restrict__ out1) {
    int idx = blockIdx.x * blockDim.x + threadIdx.x;
    int d = idx >> 3, sub = idx & 7;
    if (d >= N_NODES) return;
    const uint4* h8 = (const uint4*)hs1;      // 8 halves per uint4, 8 per row
    float acc[8];
    cvt8(h8[d * 8 + sub], acc);               // self-loop term
    int base = offs[d], c = cnt[d];
    if (c > 0) {
        int s = ebuf[base];
        int j = 0;
        for (; j + 1 < c; ++j) {
            int s2 = ebuf[base + j + 1];      // prefetch next id
            float v[8];
            cvt8(h8[s * 8 + sub], v);
#pragma unroll
            for (int k = 0; k < 8; ++k) acc[k] += v[k];
            s = s2;
        }
        float v[8];
        cvt8(h8[s * 8 + sub], v);
#pragma unroll
        for (int k = 0; k < 8; ++k) acc[k] += v[k];
    }
    float di = dinv[d];
    __half2 p0 = __floats2half2_rn(acc[0] * di, acc[1] * di);
    __half2 p1 = __floats2half2_rn(acc[2] * di, acc[3] * di);
    __half2 p2 = __floats2half2_rn(acc[4] * di, acc[5] * di);
    __half2 p3 = __floats2half2_rn(acc[6] * di, acc[7] * di);
    uint4 o;
    o.x = *(unsigned*)&p0; o.y = *(unsigned*)&p1;
    o.z = *(unsigned*)&p2; o.w = *(unsigned*)&p3;
    ((uint4*)out1)[d * 8 + sub] = o;
}

// K5: BN1 column stats over fp16 out1 — uint4 (8 halves/lane), shfl reduce.
__global__ __launch_bounds__(256) void k5_stats1(
        const __half* __restrict__ out1, float* __restrict__ stats) {
    int tid = blockIdx.x * blockDim.x + threadIdx.x;
    int gsz = gridDim.x * blockDim.x;           // multiple of 8
    const uint4* p = (const uint4*)out1;
    const int total = N_NODES * 8;              // N*64/8 vectors
    float s[8], q[8];
#pragma unroll
    for (int j = 0; j < 8; ++j) { s[j] = 0.f; q[j] = 0.f; }
    for (int i = tid; i < total; i += gsz) {    // (i&7) == (tid&7) invariant
        uint4 v = p[i];
        unsigned w[4] = {v.x, v.y, v.z, v.w};
#pragma unroll
        for (int h = 0; h < 4; ++h) {
            float2 f = __half22float2(*(__half2*)&w[h]);
            s[2*h]   += f.x; q[2*h]   = fmaf(f.x, f.x, q[2*h]);
            s[2*h+1] += f.y; q[2*h+1] = fmaf(f.y, f.y, q[2*h+1]);
        }
    }
    // lanes sharing (lane&7) hold the same col-group: reduce over bits 3..5
#pragma unroll
    for (int m = 8; m < 64; m <<= 1) {
#pragma unroll
        for (int j = 0; j < 8; ++j) {
            s[j] += __shfl_xor(s[j], m);
            q[j] += __shfl_xor(q[j], m);
        }
    }
    __shared__ float red[4][128];
    int lane = threadIdx.x & 63, wv = threadIdx.x >> 6;
    if (lane < 8) {
        int c0 = lane * 8;
#pragma unroll
        for (int j = 0; j < 8; ++j) {
            red[wv][c0 + j] = s[j];
            red[wv][64 + c0 + j] = q[j];
        }
    }
    __syncthreads();
    if (threadIdx.x < 128) {
        int t = threadIdx.x;
        float v = red[0][t] + red[1][t] + red[2][t] + red[3][t];
        unsafeAtomicAdd(&stats[t], v);          // stats[c]=sum, stats[64+c]=sumsq
    }
}

// K6: s1 = relu(bn1(out1)); hs2 = (s1 @ w2) * dinv[row], via MFMA.
// 16 rows/group/wave, grid-strided; B = w2 zero-padded to 16 cols.
__global__ __launch_bounds__(256) void k7_xw2(
        const __half* __restrict__ out1, const float* __restrict__ stats,
        const float* __restrict__ g1, const float* __restrict__ beta1,
        const float* __restrict__ w2, const float* __restrict__ dinv,
        float* __restrict__ hs2) {
    __shared__ float lsc[64], lsh[64];
    int t = threadIdx.x;
    if (t < 64) {
        float invn = 1.f / (float)N_NODES;
        float m = stats[t] * invn;
        float v = stats[64 + t] * invn - m * m;
        float inv = rsqrtf(v + BN_EPS);
        float sc = g1[t] * inv;
        lsc[t] = sc;
        lsh[t] = beta1[t] - m * sc;
    }
    __syncthreads();
    int lane = t & 63, wv = t >> 6;
    int r = lane & 15, kb = lane >> 4;
    // loop-invariant B frags and BN coefficients for this lane's k-slices
    f16x8 bf[2];
    float scr[2][8], shr[2][8];
#pragma unroll
    for (int kh = 0; kh < 2; ++kh) {
        int k0 = kh * 32 + kb * 8;
        f16x8 b;
#pragma unroll
        for (int i = 0; i < 8; ++i) {
            b[i] = (r < 2) ? (_Float16)w2[(k0 + i) * 2 + r] : (_Float16)0.f;
            scr[kh][i] = lsc[k0 + i];
            shr[kh][i] = lsh[k0 + i];
        }
        bf[kh] = b;
    }
    const int NGRP = N_NODES / 16;             // 6250
    int wid = blockIdx.x * 4 + wv;
    for (int g = wid; g < NGRP; g += K7_NBLK * 4) {
        f32x4 acc; acc[0]=0.f; acc[1]=0.f; acc[2]=0.f; acc[3]=0.f;
#pragma unroll
        for (int kh = 0; kh < 2; ++kh) {
            uint4 av = *(const uint4*)(out1 + (size_t)(g * 16 + r) * 64 + kh * 32 + kb * 8);
            unsigned w[4] = {av.x, av.y, av.z, av.w};
            f16x8 a;
#pragma unroll
            for (int h = 0; h < 4; ++h) {
                float2 f = __half22float2(*(__half2*)&w[h]);
                float y0 = fmaxf(fmaf(f.x, scr[kh][2*h],   shr[kh][2*h]),   0.f);
                float y1 = fmaxf(fmaf(f.y, scr[kh][2*h+1], shr[kh][2*h+1]), 0.f);
                a[2*h]   = (_Float16)y0;
                a[2*h+1] = (_Float16)y1;
            }
            acc = __builtin_amdgcn_mfma_f32_16x16x32_f16(a, bf[kh], acc, 0, 0, 0);
        }
        if (r < 2) {
            float4 dv = *(const float4*)&dinv[g * 16 + kb * 4];
            float dvv[4] = {dv.x, dv.y, dv.z, dv.w};
#pragma unroll
            for (int reg = 0; reg < 4; ++reg) {
                int row = g * 16 + kb * 4 + reg;
                hs2[row * 2 + r] = acc[reg] * dvv[reg];
            }
        }
    }
}

// K7: pull aggregation layer 2 + fused BN2 stats
__global__ __launch_bounds__(256) void k_pull2(
        const int* __restrict__ offs, const int* __restrict__ cnt,
        const int* __restrict__ ebuf, const float* __restrict__ dinv,
        const float* __restrict__ hs2, float* __restrict__ out2,
        float* __restrict__ stats2) {
    int d = blockIdx.x * blockDim.x + threadIdx.x;
    float o0 = 0.f, o1 = 0.f;
    if (d < N_NODES) {
        const float2* h2 = (const float2*)hs2;
        float2 self = h2[d];
        o0 = self.x; o1 = self.y;
        int base = offs[d], c = cnt[d];
        for (int j = 0; j < c; ++j) {
            int s = ebuf[base + j];
            float2 v = h2[s];
            o0 += v.x; o1 += v.y;
        }
        float di = dinv[d];
        o0 *= di; o1 *= di;
        ((float2*)out2)[d] = make_float2(o0, o1);
    }
    // block-reduce sums & sumsq (threads past N contribute 0)
    float s0 = o0, s1 = o1, q0 = o0 * o0, q1 = o1 * o1;
#pragma unroll
    for (int m = 32; m; m >>= 1) {
        s0 += __shfl_down(s0, m); s1 += __shfl_down(s1, m);
        q0 += __shfl_down(q0, m); q1 += __shfl_down(q1, m);
    }
    __shared__ float red[4][4];
    int wv = threadIdx.x >> 6;
    if ((threadIdx.x & 63) == 0) {
        red[0][wv] = s0; red[1][wv] = s1; red[2][wv] = q0; red[3][wv] = q1;
    }
    __syncthreads();
    if (threadIdx.x < 4) {
        int i = threadIdx.x;
        float v = red[i][0] + red[i][1] + red[i][2] + red[i][3];
        unsafeAtomicAdd(&stats2[i], v);
    }
}

// K8: BN2 + sigmoid + softmax epilogue
__global__ __launch_bounds__(256) void k10_head(
        const float* __restrict__ out2, const float* __restrict__ stats2,
        const float* __restrict__ g2, const float* __restrict__ beta2,
        float* __restrict__ out) {
    int r = blockIdx.x * blockDim.x + threadIdx.x;
    if (r >= N_NODES) return;
    float invn = 1.f / (float)N_NODES;
    float m0 = stats2[0] * invn, m1 = stats2[1] * invn;
    float v0 = stats2[2] * invn - m0 * m0;
    float v1 = stats2[3] * invn - m1 * m1;
    float i0 = rsqrtf(v0 + BN_EPS), i1 = rsqrtf(v1 + BN_EPS);
    float sc0 = g2[0] * i0, sc1 = g2[1] * i1;
    float sh0 = beta2[0] - m0 * sc0, sh1 = beta2[1] - m1 * sc1;
    float2 x = ((const float2*)out2)[r];
    float y0 = fmaf(x.x, sc0, sh0), y1 = fmaf(x.y, sc1, sh1);
    out[r * 2] = 1.f / (1.f + __expf(-y0));
    out[r * 2 + 1] = 1.f / (1.f + __expf(-y1));
    out[2 * N_NODES + r * 2] = 1.f / (1.f + __expf(y1 - y0));
    out[2 * N_NODES + r * 2 + 1] = 1.f / (1.f + __expf(y0 - y1));
}

extern "C" void kernel_launch(void* const* d_in, const int* in_sizes, int n_in,
                              void* d_out, int out_size, void* d_ws, size_t ws_size,
                              hipStream_t stream) {
    const int*   edge  = (const int*)d_in[0];          // (2,E): [0,E)=src, [E,2E)=dst
    const float* u_S   = (const float*)d_in[1];
    const float* w1    = (const float*)d_in[2];
    const float* g1    = (const float*)d_in[4];
    const float* beta1 = (const float*)d_in[5];
    const float* w2    = (const float*)d_in[6];
    const float* g2    = (const float*)d_in[8];
    const float* beta2 = (const float*)d_in[9];
    float* out = (float*)d_out;

    float*  ws     = (float*)d_ws;
    int*    gcur   = (int*)(ws + OFF_GCUR);
    int*    cnt    = (int*)(ws + OFF_CNT);
    float*  dinv   = ws + OFF_DINV;
    int*    offs   = (int*)(ws + OFF_OFFS);
    int*    ebuf   = (int*)(ws + OFF_EBUF);
    float*  stats1 = ws + OFF_STATS1;
    float*  stats2 = ws + OFF_STATS2;
    __half* hs1    = (__half*)(ws + OFF_HS1);
    int*    binned = (int*)(ws + OFF_BINNED);   // alias of hs1 head; dead before k3_xw1
    __half* out1   = (__half*)(ws + OFF_OUT1);
    float*  hs2    = ws + OFF_HS2;
    float*  out2   = ws + OFF_OUT2;

    const int* src = edge;
    const int* dst = edge + N_EDGES;

    k0_init<<<1, 256, 0, stream>>>(gcur, stats1);
    k_bin<<<NBLK_BIN, 256, 0, stream>>>(src, dst, gcur, binned);
    k_csr<<<NBUCK, 256, 0, stream>>>(gcur, binned, cnt, dinv, offs, ebuf);
    k3_xw1<<<(N_NODES / 16 + 3) / 4, 256, 0, stream>>>(u_S, w1, dinv, hs1);
    k_pull1<<<(N_NODES * 8 + 255) / 256, 256, 0, stream>>>(offs, cnt, ebuf, dinv, hs1, out1);
    k5_stats1<<<256, 256, 0, stream>>>(out1, stats1);
    k7_xw2<<<K7_NBLK, 256, 0, stream>>>(out1, stats1, g1, beta1, w2, dinv, hs2);
    k_pull2<<<(N_NODES + 255) / 256, 256, 0, stream>>>(offs, cnt, ebuf, dinv, hs2, out2, stats2);
    k10_head<<<(N_NODES + 255) / 256, 256, 0, stream>>>(out2, stats2, g2, beta2, out);
}